// Round 12
// baseline (173.913 us; speedup 1.0000x reference)
//
#include <hip/hip_runtime.h>
#include <math.h>

#define SEQ 2048
#define NH 8
#define HD 128
#define DIMF 1024
#define LOG2E 1.4426950408889634f
#define INVTAU 0.08838834764831845f

typedef __attribute__((ext_vector_type(8))) short bf16x8;
typedef __attribute__((ext_vector_type(8))) unsigned short us8;
typedef __attribute__((ext_vector_type(4))) float f32x4;
typedef __attribute__((ext_vector_type(16))) float f32x16;

// persistent scratch (fully rewritten every launch; no stale-state dependence)
__device__ float g_itacc[NH*SEQ];
__device__ float g_ftacc[NH*SEQ];
__device__ float g_aL[NH*SEQ];     // (itilde - csum) * log2e
__device__ float g_cmL[NH*SEQ];    // cummax(a) * log2e
__device__ float g_en[NH*SEQ];     // exp(-(csum + cummax)) = exp(-max_d)
__device__ unsigned short g_Qb[NH*SEQ*HD];  // bf16, [h][s][d]
__device__ unsigned short g_Kb[NH*SEQ*HD];
__device__ unsigned short g_Vb[NH*SEQ*HD];
__device__ unsigned short g_Vt[NH*HD*SEQ];  // bf16, [h][d][s]  (V transposed)
__device__ unsigned short g_Wb[16*3072];    // bf16, rows 0..7 = Wi, 8..15 = Wf

__device__ __forceinline__ unsigned short f2bf(float x) {
  unsigned u = __float_as_uint(x);
  u += 0x7fffu + ((u >> 16) & 1u);   // RNE
  return (unsigned short)(u >> 16);
}

__device__ __forceinline__ unsigned packbf(float lo, float hi) {
  return (unsigned)f2bf(lo) | ((unsigned)f2bf(hi) << 16);
}

// ------- kernel 1: q/k/v fp32 -> bf16 [h][s][d]  +  Wi/Wf -> bf16 (merged) -------
__global__ __launch_bounds__(256) void convert_kernel(const float* __restrict__ q,
                                                      const float* __restrict__ k,
                                                      const float* __restrict__ v,
                                                      const float* __restrict__ Wi,
                                                      const float* __restrict__ Wf) {
  const int bid = blockIdx.x;
  if (bid < 6144) {
    const int s = bid & 2047;
    const int t = bid >> 11;
    const float* src = (t == 0) ? q : (t == 1) ? k : v;
    unsigned short* dst = (t == 0) ? g_Qb : (t == 1) ? g_Kb : g_Vb;
    const int c = threadIdx.x * 4;
    const float4 f = *(const float4*)(src + s*DIMF + c);
    const int h = c >> 7, d = c & 127;
    ushort4 u;
    u.x = f2bf(f.x); u.y = f2bf(f.y); u.z = f2bf(f.z); u.w = f2bf(f.w);
    *(ushort4*)(dst + (h*SEQ + s)*HD + d) = u;
  } else {
    const int gid = (bid - 6144) * 256 + threadIdx.x;
    const int e4 = gid * 4;           // 48 blocks * 1024 = 49152 = 16*3072 exactly
    const int p = e4 / 3072;
    const int c = e4 % 3072;
    const float* src = (p < 8) ? (Wi + p*3072 + c) : (Wf + (p-8)*3072 + c);
    const float4 f = *(const float4*)src;
    ushort4 u;
    u.x = f2bf(f.x); u.y = f2bf(f.y); u.z = f2bf(f.z); u.w = f2bf(f.w);
    *(ushort4*)(g_Wb + p*3072 + c) = u;
  }
}

// ------- kernel 2: V transpose  g_Vb[h][s][d] -> g_Vt[h][d][s] -------
__global__ __launch_bounds__(256) void vtrans_kernel() {
  __shared__ __align__(16) unsigned short Ts[64*72];
  const int h  = blockIdx.x;
  const int s0 = blockIdx.y * 64;
  const int d0 = blockIdx.z * 64;
  const int t = threadIdx.x;
  { // load 64 s-rows x 64 d-cols, coalesced
    const int sr = t >> 2;
    const int c  = (t & 3) * 16;
    const unsigned short* src = g_Vb + (h*SEQ + s0 + sr)*HD + d0 + c;
    *(us8*)&Ts[sr*72 + c]     = *(const us8*)&src[0];
    *(us8*)&Ts[sr*72 + c + 8] = *(const us8*)&src[8];
  }
  __syncthreads();
  { // store: wave w covers s-cols [w*16,w*16+16), lane l = output d-row
    const int w = t >> 6, l = t & 63;
    unsigned short outv[16];
    #pragma unroll
    for (int j = 0; j < 16; ++j) outv[j] = Ts[(w*16 + j)*72 + l];
    unsigned short* dst = g_Vt + (h*HD + d0 + l)*SEQ + s0 + w*16;
    *(us8*)&dst[0] = *(us8*)&outv[0];
    *(us8*)&dst[8] = *(us8*)&outv[8];
  }
}

// ------- kernel 3: gate projections via MFMA (M=2048, N=16, K=3072) -------
__global__ __launch_bounds__(256) void gates_kernel() {
  __shared__ f32x4 red[4][64];
  const int tid = threadIdx.x;
  const int wave = tid >> 6, lane = tid & 63;
  const int q4 = lane >> 4, l16 = lane & 15;
  const int s0 = blockIdx.x * 16;
  f32x4 acc = {0.f, 0.f, 0.f, 0.f};
  #pragma unroll 8
  for (int ks = wave*24; ks < wave*24 + 24; ++ks) {
    const int k0 = ks*32 + q4*8;          // global k of this lane's 8 elems
    const int tsel = k0 >> 10;
    const int rem = k0 & 1023;
    const int hh = rem >> 7, dd = rem & 127;
    const unsigned short* base = (tsel == 0) ? g_Qb : (tsel == 1) ? g_Kb : g_Vb;
    const bf16x8 a = *(const bf16x8*)&base[(hh*SEQ + s0 + l16)*HD + dd];
    const bf16x8 b = *(const bf16x8*)&g_Wb[l16*3072 + k0];
    acc = __builtin_amdgcn_mfma_f32_16x16x32_bf16(a, b, acc, 0, 0, 0);
  }
  red[wave][lane] = acc;
  __syncthreads();
  if (wave == 0) {
    f32x4 s = red[0][lane];
    #pragma unroll
    for (int w = 1; w < 4; ++w) s += red[w][lane];
    #pragma unroll
    for (int r = 0; r < 4; ++r) {
      const int sg = s0 + 4*q4 + r;       // C/D: row = quad*4+reg, col = l16
      if (l16 < 8) g_itacc[l16*SEQ + sg] = s[r];
      else         g_ftacc[(l16-8)*SEQ + sg] = s[r];
    }
  }
}

// ------- kernel 4: per-head scans (block scan, 256 threads, 8 elems/thread) -------
__global__ __launch_bounds__(256) void scan_kernel(const float* __restrict__ Wi_b,
                                                   const float* __restrict__ Wf_b) {
  __shared__ float Wsum[4];
  __shared__ float Wmax[4];
  const int h = blockIdx.x;
  const int t = threadIdx.x;
  const int wave = t >> 6, lane = t & 63;
  const float ib = Wi_b[h];
  const float fb = Wf_b[h];
  const int base = h*SEQ + t*8;

  float it[8], ft[8];
  *(float4*)&it[0] = *(const float4*)&g_itacc[base];
  *(float4*)&it[4] = *(const float4*)&g_itacc[base+4];
  *(float4*)&ft[0] = *(const float4*)&g_ftacc[base];
  *(float4*)&ft[4] = *(const float4*)&g_ftacc[base+4];

  float cs[8];
  float run = 0.f;
  #pragma unroll
  for (int j = 0; j < 8; ++j) {
    const float f = ft[j] + fb;
    const float ls = fminf(f, 0.f) - log1pf(expf(-fabsf(f)));  // logsigmoid
    run += ls;
    cs[j] = run;
  }
  float x = run;
  #pragma unroll
  for (int off = 1; off < 64; off <<= 1) {
    const float tv = __shfl_up(x, off, 64);
    if (lane >= off) x += tv;
  }
  const float wexcl = x - run;
  if (lane == 63) Wsum[wave] = x;
  __syncthreads();
  float boff = 0.f;
  #pragma unroll
  for (int w = 0; w < 4; ++w) if (w < wave) boff += Wsum[w];
  const float cbase = boff + wexcl;

  float a[8], am[8], csum[8];
  float m = -__builtin_inff();
  #pragma unroll
  for (int j = 0; j < 8; ++j) {
    csum[j] = cbase + cs[j];
    a[j] = (it[j] + ib) - csum[j];
    m = fmaxf(m, a[j]);
    am[j] = m;
  }
  float y = m;
  #pragma unroll
  for (int off = 1; off < 64; off <<= 1) {
    const float tv = __shfl_up(y, off, 64);
    if (lane >= off) y = fmaxf(y, tv);
  }
  float e = __shfl_up(y, 1, 64);
  if (lane == 0) e = -__builtin_inff();
  if (lane == 63) Wmax[wave] = y;
  __syncthreads();
  float bmax = -__builtin_inff();
  #pragma unroll
  for (int w = 0; w < 4; ++w) if (w < wave) bmax = fmaxf(bmax, Wmax[w]);
  const float pre = fmaxf(bmax, e);

  float oa[8], ocm[8], oen[8];
  #pragma unroll
  for (int j = 0; j < 8; ++j) {
    const float cm = fmaxf(pre, am[j]);
    oa[j]  = a[j] * LOG2E;
    ocm[j] = cm * LOG2E;
    oen[j] = expf(-(csum[j] + cm));
  }
  *(float4*)&g_aL[base]    = *(float4*)&oa[0];
  *(float4*)&g_aL[base+4]  = *(float4*)&oa[4];
  *(float4*)&g_cmL[base]   = *(float4*)&ocm[0];
  *(float4*)&g_cmL[base+4] = *(float4*)&ocm[4];
  *(float4*)&g_en[base]    = *(float4*)&oen[0];
  *(float4*)&g_en[base+4]  = *(float4*)&oen[4];
}

// ------- kernel 5: fused attention + maxit normalize + GroupNorm -------
// 8-WAVE (512-thread) d-split: round 11's per-wave body (88 VGPR, passed) but
// visits are 256 j wide with 8 waves. Wave w: QK+softmax for j-EIGHTH w;
// PV for d-quarter (w&3) over j-half (w>>2) -> acc stays 16 VGPRs; the two
// j-half accs merge once in the epilogue (LDS overlay). Why: round 11's
// complement pairing balanced totals but not CONCURRENCY -- the light block
// dies in 1/16 of the heavy block's life, leaving 1 wave/SIMD for most of the
// makespan. An 8-wave block alone on a CU sustains 2 waves/SIMD; with the
// paired block alive it's 4 (4 x 128 VGPR = full RF).
// LDS is PADDED to 56KB deliberately: at 512 threads the backend caps VGPR by
// its occupancy heuristic (rounds 4-6: 68.6KB LDS -> 2 blocks/CU -> 128-reg
// cap); a ~35KB kernel risks a 4-block 64-reg cap -> spill. Grid only supplies
// 2 blocks/CU, so the padding costs nothing.
// grid = (NH, 64): bid%8 = head (XCD L2 affinity); t = y<32 ? 63-y : y-32.
__global__ __launch_bounds__(512, 1) void attn_kernel(const float* __restrict__ gnw,
                                                      const float* __restrict__ gnb,
                                                      float* __restrict__ out) {
  __shared__ __align__(16) unsigned char smem[57344];
  us8 (*Ps)[8][2][64] = (us8 (*)[8][2][64])smem;     // 32KB: [buf][eighth][ph][lane]
  float (*Ocomb)[32][33] = (float (*)[32][33])smem;  // epilogue overlay (16.9KB)
  __shared__ float Sq[8][32];
  __shared__ float Sc[32];
  __shared__ float Sn1[4][32];
  __shared__ float Sn2[4][32];
  __shared__ float Mu[32];
  __shared__ float Rstd[32];

  const int h = blockIdx.x;
  const int y = blockIdx.y;            // 0..63
  const int t = (y < 32) ? (63 - y) : (y - 32);   // heavy-first complement pairing
  const int i0 = 32*t;
  const int imax = i0 + 31;
  const int nv = (imax >> 8) + 1;      // 256-col visits (1..8)

  const int tid  = threadIdx.x;
  const int w    = tid >> 6;           // wave 0..7
  const int lane = tid & 63;
  const int l31  = lane & 31;
  const int hi   = lane >> 5;
  const int dq   = w & 3;              // PV d-quarter
  const int jh   = w >> 2;             // PV j-half

  const unsigned short* Kgh = g_Kb + (h*SEQ + l31)*HD + hi*8;          // + jw*HD + ks*16
  const unsigned short* Vgh = g_Vt + (h*HD + 32*dq + l31)*SEQ + hi*8;  // + j
  const float*          aLh = g_aL + h*SEQ + 4*hi;                     // + jw + 8*rq

  // Q B-fragments (n = i = lane&31)
  bf16x8 qf[8];
  {
    const unsigned short* Qg = g_Qb + (h*SEQ + i0 + l31)*HD + hi*8;
    #pragma unroll
    for (int ks = 0; ks < 8; ++ks) qf[ks] = *(const bf16x8*)&Qg[ks*16];
  }
  const float cm = g_cmL[h*SEQ + i0 + l31];
  const int   ig = i0 + l31;

  f32x16 acc;
  #pragma unroll
  for (int e = 0; e < 16; ++e) acc[e] = 0.f;
  float rs = 0.f;

  for (int jc = 0; jc < nv; ++jc) {
    const int jb  = jc*256;
    const int jw  = jb + 32*w;         // this wave's QK j-eighth
    const int buf = jc & 1;

    // V for this wave's PV slice (d-quarter dq, j-half jh): consumed last,
    // latency hides under QK+softmax.
    bf16x8 vb[8];
    #pragma unroll
    for (int q2 = 0; q2 < 4; ++q2)
      #pragma unroll
      for (int ph = 0; ph < 2; ++ph)
        vb[q2*2 + ph] = *(const bf16x8*)&Vgh[jb + jh*128 + q2*32 + 16*ph];

    if (jw <= imax) {
      // batched K fragments (single exposed L2 latency)
      bf16x8 kf[8];
      #pragma unroll
      for (int ks = 0; ks < 8; ++ks) kf[ks] = *(const bf16x8*)&Kgh[jw*HD + ks*16];
      float4 aLq[4];
      #pragma unroll
      for (int rq = 0; rq < 4; ++rq) aLq[rq] = *(const float4*)&aLh[jw + 8*rq];

      f32x16 s;
      #pragma unroll
      for (int e = 0; e < 16; ++e) s[e] = 0.f;
      #pragma unroll
      for (int ks = 0; ks < 8; ++ks)
        s = __builtin_amdgcn_mfma_f32_32x32x16_bf16(kf[ks], qf[ks], s, 0, 0, 0);

      const bool needMask = (jw + 31 > i0);   // wave-uniform
      #pragma unroll
      for (int ph = 0; ph < 2; ++ph) {
        float pv[8];
        #pragma unroll
        for (int rr = 0; rr < 8; ++rr) {
          const int r  = 8*ph + rr;
          const int rq = r >> 2;
          const float aL = ((const float*)&aLq[rq])[r & 3];
          float p = s[r] * (exp2f(aL - cm) * INVTAU);
          if (needMask) {
            const int jg = jw + 8*rq + 4*hi + (r & 3);
            if (jg > ig) p = 0.f;
          }
          rs += p;
          pv[rr] = p;
        }
        const unsigned w0 = packbf(pv[0], pv[1]);
        const unsigned w1 = packbf(pv[2], pv[3]);
        const unsigned w2 = packbf(pv[4], pv[5]);
        const unsigned w3 = packbf(pv[6], pv[7]);
        const auto p0 = __builtin_amdgcn_permlane32_swap(w0, w2, false, false);
        const auto p1 = __builtin_amdgcn_permlane32_swap(w1, w3, false, false);
        union { unsigned u[4]; us8 sv; } fr;
        fr.u[0] = p0[0]; fr.u[1] = p1[0]; fr.u[2] = p0[1]; fr.u[3] = p1[1];
        Ps[buf][w][ph][lane] = fr.sv;
      }
    } else {
      // zero-fill inactive eighth so PV runs unconditionally
      const us8 z = {0, 0, 0, 0, 0, 0, 0, 0};
      Ps[buf][w][0][lane] = z;
      Ps[buf][w][1][lane] = z;
    }
    __syncthreads();   // publish Ps[buf]

    // PV: this wave's d-quarter x j-half; fully unrolled, zero loads inside
    #pragma unroll
    for (int q2 = 0; q2 < 4; ++q2)
      #pragma unroll
      for (int ph = 0; ph < 2; ++ph) {
        const bf16x8 pf = *(const bf16x8*)&Ps[buf][4*jh + q2][ph][lane];
        acc = __builtin_amdgcn_mfma_f32_32x32x16_bf16(pf, vb[q2*2 + ph], acc, 0, 0, 0);
      }
  }

  // ---- epilogue: merge j-halves, rowsum, maxit scale, GroupNorm ----
  {
    const float rs2 = rs + __shfl_xor(rs, 32, 64);   // combine hi halves (same i)
    if (hi == 0) Sq[w][l31] = rs2;
  }
  __syncthreads();                     // Ps reads done; Sq published
  if (w >= 4) {                        // waves 4..7 stage j-half-1 acc (overlay)
    #pragma unroll
    for (int r = 0; r < 16; ++r) {
      const int row = (r & 3) + 8*(r >> 2) + 4*hi;
      Ocomb[w - 4][row][l31] = acc[r];
    }
  }
  if (w == 0 && lane < 32) {
    float S = 0.f;
    #pragma unroll
    for (int k = 0; k < 8; ++k) S += Sq[k][lane];
    const float en = g_en[h*SEQ + i0 + lane];
    Sc[lane] = 1.f / (fmaxf(fabsf(S), en) + 1e-6f);
  }
  __syncthreads();

  float o[16];
  if (w < 4) {                         // waves 0..3 hold full O after merge
    #pragma unroll
    for (int r = 0; r < 16; ++r) {
      const int irow = (r & 3) + 8*(r >> 2) + 4*hi;
      const float xv = (acc[r] + Ocomb[w][irow][l31]) * Sc[irow];
      o[r] = xv;
      float a = xv, b = xv * xv;
      #pragma unroll
      for (int m = 1; m < 32; m <<= 1) { a += __shfl_xor(a, m, 32); b += __shfl_xor(b, m, 32); }
      if (l31 == 0) { Sn1[w][irow] = a; Sn2[w][irow] = b; }
    }
  }
  __syncthreads();
  if (w == 0 && lane < 32) {
    const float s1 = Sn1[0][lane] + Sn1[1][lane] + Sn1[2][lane] + Sn1[3][lane];
    const float s2 = Sn2[0][lane] + Sn2[1][lane] + Sn2[2][lane] + Sn2[3][lane];
    const float mean = s1 * (1.f/128.f);
    const float var  = s2 * (1.f/128.f) - mean*mean;
    Mu[lane]   = mean;
    Rstd[lane] = rsqrtf(var + 1e-5f);
  }
  __syncthreads();

  if (w < 4) {
    const float gwv = gnw[h*HD + 32*dq + l31];
    const float gbv = gnb[h*HD + 32*dq + l31];
    #pragma unroll
    for (int r = 0; r < 16; ++r) {
      const int irow = (r & 3) + 8*(r >> 2) + 4*hi;
      out[(i0 + irow)*DIMF + h*HD + 32*dq + l31] =
          (o[r] - Mu[irow]) * Rstd[irow] * gwv + gbv;
    }
  }
}

extern "C" void kernel_launch(void* const* d_in, const int* in_sizes, int n_in,
                              void* d_out, int out_size, void* d_ws, size_t ws_size,
                              hipStream_t stream) {
  (void)in_sizes; (void)n_in; (void)out_size; (void)d_ws; (void)ws_size;
  const float* q    = (const float*)d_in[0];
  const float* k    = (const float*)d_in[1];
  const float* v    = (const float*)d_in[2];
  const float* Wi_w = (const float*)d_in[3];
  const float* Wi_b = (const float*)d_in[4];
  const float* Wf_w = (const float*)d_in[5];
  const float* Wf_b = (const float*)d_in[6];
  const float* gnw  = (const float*)d_in[7];
  const float* gnb  = (const float*)d_in[8];
  float* out = (float*)d_out;

  convert_kernel<<<dim3(6192), 256, 0, stream>>>(q, k, v, Wi_w, Wf_w);
  vtrans_kernel<<<dim3(NH, SEQ/64, HD/64), 256, 0, stream>>>();
  gates_kernel<<<dim3(128), 256, 0, stream>>>();
  scan_kernel<<<dim3(NH), 256, 0, stream>>>(Wi_b, Wf_b);
  attn_kernel<<<dim3(NH, 64), 512, 0, stream>>>(gnw, gnb, out);
}